// Round 1
// baseline (259.649 us; speedup 1.0000x reference)
//
#include <hip/hip_runtime.h>
#include <hip/hip_bf16.h>
#include <math.h>

typedef __bf16 bf16;
typedef __attribute__((ext_vector_type(8))) __bf16 bf16x8;
typedef __attribute__((ext_vector_type(4))) __bf16 bf16x4;
typedef __attribute__((ext_vector_type(4))) float f32x4;

#define LOG2E 1.4426950408889634f

// ---------------------------------------------------------------- cast fp32 -> bf16
__global__ void cast_kernel(const float* __restrict__ src, bf16* __restrict__ dst, int n4) {
  int i = blockIdx.x * blockDim.x + threadIdx.x;
  int stride = gridDim.x * blockDim.x;
  for (; i < n4; i += stride) {
    float4 v = ((const float4*)src)[i];
    bf16x4 o = { (bf16)v.x, (bf16)v.y, (bf16)v.z, (bf16)v.w };
    ((bf16x4*)dst)[i] = o;
  }
}

// ---------------------------------------------------------------- GEMM: C = A @ W^T (+bias)(+res)(+gelu)
// A [N,K] bf16 row-major, W [O,K] bf16 row-major (both K-contiguous).
// MODE 0: out bf16 = acc + bias
// MODE 1: out f32  = acc + bias + res
// MODE 2: out bf16 = gelu_erf(acc + bias)
template<int MODE>
__launch_bounds__(256)
__global__ void gemm_kernel(const bf16* __restrict__ A, const bf16* __restrict__ W,
                            const float* __restrict__ bias, const float* __restrict__ res,
                            void* __restrict__ out, int K, int O) {
  __shared__ bf16 As[128][80];   // stride 80 bf16 = 160B = 40 banks -> uniform spread
  __shared__ bf16 Bs[128][80];
  const int t    = threadIdx.x;
  const int lane = t & 63;
  const int wave = t >> 6;
  const int wr = (wave >> 1) * 64;
  const int wc = (wave & 1) * 64;
  const int n0 = blockIdx.y * 128;
  const int o0 = blockIdx.x * 128;

  f32x4 zero = {0.f, 0.f, 0.f, 0.f};
  f32x4 acc[4][4];
#pragma unroll
  for (int m = 0; m < 4; m++)
#pragma unroll
    for (int n = 0; n < 4; n++) acc[m][n] = zero;

  const int r_l = t >> 3;        // staging row base 0..31
  const int c_l = (t & 7) * 8;   // staging chunk offset (elems)
  const int fr  = lane & 15;
  const int fg8 = (lane >> 4) * 8;

  for (int k0 = 0; k0 < K; k0 += 64) {
    __syncthreads();
#pragma unroll
    for (int j = 0; j < 4; j++) {
      int row = r_l + 32 * j;
      *(bf16x8*)&As[row][c_l] = *(const bf16x8*)&A[(size_t)(n0 + row) * K + k0 + c_l];
      *(bf16x8*)&Bs[row][c_l] = *(const bf16x8*)&W[(size_t)(o0 + row) * K + k0 + c_l];
    }
    __syncthreads();
#pragma unroll
    for (int kf = 0; kf < 2; kf++) {
      bf16x8 a[4], b[4];
#pragma unroll
      for (int m = 0; m < 4; m++) a[m] = *(const bf16x8*)&As[wr + m * 16 + fr][kf * 32 + fg8];
#pragma unroll
      for (int n = 0; n < 4; n++) b[n] = *(const bf16x8*)&Bs[wc + n * 16 + fr][kf * 32 + fg8];
#pragma unroll
      for (int m = 0; m < 4; m++)
#pragma unroll
        for (int n = 0; n < 4; n++)
          acc[m][n] = __builtin_amdgcn_mfma_f32_16x16x32_bf16(a[m], b[n], acc[m][n], 0, 0, 0);
    }
  }

  const int fg4 = (lane >> 4) * 4;
#pragma unroll
  for (int m = 0; m < 4; m++) {
#pragma unroll
    for (int n = 0; n < 4; n++) {
      int col = o0 + wc + n * 16 + fr;
      float bv = bias[col];
#pragma unroll
      for (int r = 0; r < 4; r++) {
        int row = n0 + wr + m * 16 + fg4 + r;
        float v = acc[m][n][r] + bv;
        if constexpr (MODE == 1) {
          v += res[(size_t)row * O + col];
          ((float*)out)[(size_t)row * O + col] = v;
        } else if constexpr (MODE == 2) {
          v = 0.5f * v * (1.0f + erff(v * 0.70710678118654752f));
          ((bf16*)out)[(size_t)row * O + col] = (bf16)v;
        } else {
          ((bf16*)out)[(size_t)row * O + col] = (bf16)v;
        }
      }
    }
  }
}

// ---------------------------------------------------------------- flash attention
// qkv [4096][2304] bf16 (q|k|v each 768 = 8 heads * 96). bias [B][L][L] f32.
// ctx out [4096][768] bf16. Block: 4 waves, each wave owns 16 q-rows; KV tiles of 64.
// Swapped layout: S^T = K*Q^T so lane&15 = q; PV as ctx^T = V^T * P.
__launch_bounds__(256)
__global__ void attn_kernel(const bf16* __restrict__ qkv, const float* __restrict__ bias,
                            bf16* __restrict__ ctx) {
  __shared__ bf16 Ks[64][120];     // 240B stride = 60 banks -> uniform
  __shared__ bf16 Vt[96][80];      // transposed V: [hd][kv]
  __shared__ bf16 Pl[4][16][80];   // per-wave P^T: [q][kv]
  const int t    = threadIdx.x;
  const int lane = t & 63;
  const int wave = t >> 6;
  const int qb = blockIdx.x;
  const int h  = blockIdx.y;
  const int b  = blockIdx.z;
  const int L  = 2048;
  const size_t base = (size_t)b * L * 2304;
  const int q0 = qb * 64 + wave * 16;
  const int fq = lane & 15;
  const int g  = lane >> 4;

  // Q fragments: lane holds Q[q0+fq][f*32 + g*8 + j]
  bf16x8 qf[3];
  {
    const bf16* qp = qkv + base + (size_t)(q0 + fq) * 2304 + h * 96;
#pragma unroll
    for (int f = 0; f < 3; f++) qf[f] = *(const bf16x8*)(qp + f * 32 + g * 8);
  }

  float m_run = -1e30f, l_run = 0.f;
  f32x4 zero = {0.f, 0.f, 0.f, 0.f};
  f32x4 o_acc[6];
#pragma unroll
  for (int i = 0; i < 6; i++) o_acc[i] = zero;

  const float scale = 0.10206207261596575f;  // 1/sqrt(96)
  const float* bp = bias + ((size_t)b * L + (q0 + fq)) * L;

  const int kvr  = t & 63;
  const int offb = (t >> 6) * 8;

  for (int kv0 = 0; kv0 < L; kv0 += 64) {
    __syncthreads();
    {  // stage K (row-major) and V (transposed)
      const bf16* kp = qkv + base + (size_t)(kv0 + kvr) * 2304 + 768 + h * 96;
      const bf16* vp = kp + 768;
#pragma unroll
      for (int i = 0; i < 3; i++) {
        int off = offb + 32 * i;
        *(bf16x8*)&Ks[kvr][off] = *(const bf16x8*)(kp + off);
        bf16x8 vv = *(const bf16x8*)(vp + off);
#pragma unroll
        for (int j = 0; j < 8; j++) Vt[off + j][kvr] = vv[j];
      }
    }
    __syncthreads();

    // S^T tile [64 kv][16 q]: lane holds q=fq, kv = kvt*16 + g*4 + r
    f32x4 s[4];
#pragma unroll
    for (int kvt = 0; kvt < 4; kvt++) {
      s[kvt] = zero;
#pragma unroll
      for (int f = 0; f < 3; f++) {
        bf16x8 kfr = *(const bf16x8*)&Ks[kvt * 16 + fq][f * 32 + g * 8];
        s[kvt] = __builtin_amdgcn_mfma_f32_16x16x32_bf16(kfr, qf[f], s[kvt], 0, 0, 0);
      }
    }

    float p[4][4];
    float vmax = -1e30f;
#pragma unroll
    for (int kvt = 0; kvt < 4; kvt++) {
      float4 bv = *(const float4*)(bp + kv0 + kvt * 16 + g * 4);
#pragma unroll
      for (int r = 0; r < 4; r++) {
        float sv = s[kvt][r] * scale + (&bv.x)[r];
        p[kvt][r] = sv;
        vmax = fmaxf(vmax, sv);
      }
    }
    vmax = fmaxf(vmax, __shfl_xor(vmax, 16));
    vmax = fmaxf(vmax, __shfl_xor(vmax, 32));
    float m_new = fmaxf(m_run, vmax);
    float corr = exp2f((m_run - m_new) * LOG2E);
    float rsum = 0.f;
#pragma unroll
    for (int kvt = 0; kvt < 4; kvt++) {
      bf16x4 pb;
#pragma unroll
      for (int r = 0; r < 4; r++) {
        float pv = exp2f((p[kvt][r] - m_new) * LOG2E);
        rsum += pv;
        pb[r] = (bf16)pv;
      }
      *(bf16x4*)&Pl[wave][fq][kvt * 16 + g * 4] = pb;
    }
    rsum += __shfl_xor(rsum, 16);
    rsum += __shfl_xor(rsum, 32);
    l_run = l_run * corr + rsum;
    m_run = m_new;
#pragma unroll
    for (int i = 0; i < 6; i++)
#pragma unroll
      for (int r = 0; r < 4; r++) o_acc[i][r] *= corr;
    __syncthreads();

    // PV: ctx^T += V^T * P  (A = V^T from Vt, B = P from Pl, both contiguous b128)
#pragma unroll
    for (int kf = 0; kf < 2; kf++) {
      bf16x8 pfrag = *(const bf16x8*)&Pl[wave][fq][kf * 32 + g * 8];
#pragma unroll
      for (int ht = 0; ht < 6; ht++) {
        bf16x8 vfrag = *(const bf16x8*)&Vt[ht * 16 + fq][kf * 32 + g * 8];
        o_acc[ht] = __builtin_amdgcn_mfma_f32_16x16x32_bf16(vfrag, pfrag, o_acc[ht], 0, 0, 0);
      }
    }
  }

  // epilogue: lane holds ctx^T[hd = ht*16 + g*4 + r][q = fq]
  float inv = 1.0f / l_run;
  bf16* cp = ctx + ((size_t)b * L + (q0 + fq)) * 768 + h * 96;
#pragma unroll
  for (int ht = 0; ht < 6; ht++) {
    bf16x4 ov;
#pragma unroll
    for (int r = 0; r < 4; r++) ov[r] = (bf16)(o_acc[ht][r] * inv);
    *(bf16x4*)(cp + ht * 16 + g * 4) = ov;
  }
}

// ---------------------------------------------------------------- LayerNorm (row = block); in may alias outf
__launch_bounds__(256)
__global__ void ln_kernel(const float* in, const float* __restrict__ gamma,
                          const float* __restrict__ beta, float* outf, bf16* outb) {
  const int row = blockIdx.x;
  const int t = threadIdx.x;
  const float* rp = in + (size_t)row * 768;
  float v[3];
#pragma unroll
  for (int i = 0; i < 3; i++) v[i] = rp[t + 256 * i];
  float s = v[0] + v[1] + v[2];
  float ss = v[0] * v[0] + v[1] * v[1] + v[2] * v[2];
#pragma unroll
  for (int off = 1; off < 64; off <<= 1) {
    s += __shfl_xor(s, off);
    ss += __shfl_xor(ss, off);
  }
  __shared__ float red[8];
  if ((t & 63) == 0) { red[(t >> 6) * 2] = s; red[(t >> 6) * 2 + 1] = ss; }
  __syncthreads();
  s = red[0] + red[2] + red[4] + red[6];
  ss = red[1] + red[3] + red[5] + red[7];
  float mu = s * (1.0f / 768.0f);
  float var = ss * (1.0f / 768.0f) - mu * mu;
  float rs = rsqrtf(var + 1e-5f);
#pragma unroll
  for (int i = 0; i < 3; i++) {
    int col = t + 256 * i;
    float y = (v[i] - mu) * rs * gamma[col] + beta[col];
    outf[(size_t)row * 768 + col] = y;
    if (outb) outb[(size_t)row * 768 + col] = (bf16)y;
  }
}

// ---------------------------------------------------------------- launch
extern "C" void kernel_launch(void* const* d_in, const int* in_sizes, int n_in,
                              void* d_out, int out_size, void* d_ws, size_t ws_size,
                              hipStream_t stream) {
  (void)in_sizes; (void)n_in; (void)out_size; (void)ws_size;
  const float* x     = (const float*)d_in[0];
  const float* ab    = (const float*)d_in[1];
  const float* w_qkv = (const float*)d_in[2];
  const float* b_qkv = (const float*)d_in[3];
  const float* w_out = (const float*)d_in[4];
  const float* b_out = (const float*)d_in[5];
  const float* W1    = (const float*)d_in[6];
  const float* b1    = (const float*)d_in[7];
  const float* W2    = (const float*)d_in[8];
  const float* b2    = (const float*)d_in[9];
  const float* g1    = (const float*)d_in[10];
  const float* be1   = (const float*)d_in[11];
  const float* g2    = (const float*)d_in[12];
  const float* be2   = (const float*)d_in[13];
  float* outf = (float*)d_out;

  char* p = (char*)d_ws;
  bf16* xb    = (bf16*)p;  p += (size_t)4096 * 768 * 2;
  bf16* qkv   = (bf16*)p;  p += (size_t)4096 * 2304 * 2;
  bf16* ctx   = (bf16*)p;  p += (size_t)4096 * 768 * 2;
  float* x1f  = (float*)p; p += (size_t)4096 * 768 * 4;
  bf16* x1b   = (bf16*)p;  p += (size_t)4096 * 768 * 2;
  bf16* hbuf  = (bf16*)p;  p += (size_t)4096 * 2048 * 2;
  bf16* wqkvb = (bf16*)p;  p += (size_t)2304 * 768 * 2;
  bf16* woutb = (bf16*)p;  p += (size_t)768 * 768 * 2;
  bf16* w1b   = (bf16*)p;  p += (size_t)2048 * 768 * 2;
  bf16* w2b   = (bf16*)p;  p += (size_t)768 * 2048 * 2;

  cast_kernel<<<1024, 256, 0, stream>>>(x, xb, 4096 * 768 / 4);
  cast_kernel<<<512, 256, 0, stream>>>(w_qkv, wqkvb, 2304 * 768 / 4);
  cast_kernel<<<256, 256, 0, stream>>>(w_out, woutb, 768 * 768 / 4);
  cast_kernel<<<512, 256, 0, stream>>>(W1, w1b, 2048 * 768 / 4);
  cast_kernel<<<512, 256, 0, stream>>>(W2, w2b, 768 * 2048 / 4);

  // qkv = x @ in_proj_w^T + b
  gemm_kernel<0><<<dim3(18, 32), 256, 0, stream>>>(xb, wqkvb, b_qkv, nullptr, qkv, 768, 2304);
  // attention
  attn_kernel<<<dim3(32, 8, 2), 256, 0, stream>>>(qkv, ab, ctx);
  // res1 = ctx @ out_w^T + out_b + x   (into d_out as scratch)
  gemm_kernel<1><<<dim3(6, 32), 256, 0, stream>>>(ctx, woutb, b_out, x, outf, 768, 768);
  // x1 = LN(res1)
  ln_kernel<<<4096, 256, 0, stream>>>(outf, g1, be1, x1f, x1b);
  // h = gelu(x1 @ W1^T + b1)
  gemm_kernel<2><<<dim3(16, 32), 256, 0, stream>>>(x1b, w1b, b1, nullptr, hbuf, 768, 2048);
  // res2 = h @ W2^T + b2 + x1   (into d_out)
  gemm_kernel<1><<<dim3(6, 32), 256, 0, stream>>>(hbuf, w2b, b2, x1f, outf, 2048, 768);
  // out = LN(res2), in place
  ln_kernel<<<4096, 256, 0, stream>>>(outf, g2, be2, outf, nullptr);
}